// Round 5
// baseline (134.038 us; speedup 1.0000x reference)
//
#include <hip/hip_runtime.h>

// ContrastiveLoss on MI355X (gfx950) — round 5
// loss = (1/n) sum_i [ P_i*(10+log z_i) - 10*possum_i ]
//   z_i      = sum_{j != i} exp(10*dot_ij - 10)   (bf16 MFMA, no barriers)
//   possum_i = e_i . C_{lab_i} - 1                (class centroids, f32, exact)
// R5 vs R4: raw v_exp_f32 (OCML exp2f was ~10 insts/call), pacc/labels removed
// from the hot loop (centroid path), VGPR drop -> 5 waves/SIMD.

#define N 8192
#define D 128
#define JSPLIT 32         // grid.y; j-window = 256 rows
#define IBLK 256          // i-rows per block (4 waves x 64)
#define K2E 14.4269504088896340736f   // 10*log2(e)

typedef __bf16 bf16x8 __attribute__((ext_vector_type(8)));
typedef float f32x4 __attribute__((ext_vector_type(4)));

// ws layout (bytes)
#define EBF_OFF  0          // bf16 E, fragment-major: 2 MB
#define C_OFF    2097152    // class sums: 100*128*4 = 51200
#define CNT_OFF  2148352    // class counts: 100*4, padded to 512
#define Z_OFF    2148864    // z per row: 32 KB
#define ZERO_SZ  (51200 + 512 + 32768)

__device__ __forceinline__ unsigned short f32_to_bf16_rne(float f) {
    unsigned int u = __float_as_uint(f);
    u += 0x7fffu + ((u >> 16) & 1u);
    return (unsigned short)(u >> 16);
}

__device__ __forceinline__ float fast_exp2(float x) {
#if __has_builtin(__builtin_amdgcn_exp2f)
    return __builtin_amdgcn_exp2f(x);   // raw v_exp_f32; arg in [-29, 0.3]
#else
    return exp2f(x);
#endif
}

__device__ __forceinline__ float fast_log2(float x) {
#if __has_builtin(__builtin_amdgcn_logf)
    return __builtin_amdgcn_logf(x);    // raw v_log_f32
#else
    return log2f(x);
#endif
}

// Fragment-major layout of E:
//   row r: grp = r>>4, col = r&15 ; element k: c = k>>5, q = (k>>3)&3, jj = k&7
//   byte = grp*4096 + c*1024 + q*256 + col*16 + jj*2
// A/B fragment chunk c of 16-row group g: lane reads 16B at g*4096 + c*1024 + lane*16
// -> one fully-coalesced 1KB global_load_dwordx4 per chunk.

// Kernel 1: normalize -> fragment-major bf16 E; class centroids + histogram.
__global__ __launch_bounds__(256) void prep_kernel(
        const float* __restrict__ emb, const int* __restrict__ labels,
        unsigned char* __restrict__ ebf, float* __restrict__ C,
        int* __restrict__ cnt) {
    const int wave = threadIdx.x >> 6;
    const int lane = threadIdx.x & 63;
    const int row  = blockIdx.x * 4 + wave;

    const float2 v = *(const float2*)(emb + (size_t)row * D + lane * 2);
    float ss = v.x * v.x + v.y * v.y;
    #pragma unroll
    for (int off = 32; off; off >>= 1) ss += __shfl_xor(ss, off);
    const float inv = 1.0f / fmaxf(sqrtf(ss), 1e-12f);

    const int grp = row >> 4, col = row & 15;
    const int c = lane >> 4, q = (lane >> 2) & 3, j2 = lane & 3;
    unsigned int packed = (unsigned int)f32_to_bf16_rne(v.x * inv) |
                          ((unsigned int)f32_to_bf16_rne(v.y * inv) << 16);
    *(unsigned int*)(ebf + grp * 4096 + c * 1024 + q * 256 + col * 16 + j2 * 4) = packed;

    // centroid accumulation; rotate element per row to de-hotspot atomics
    const int lab = labels[row];
    const int e0  = (lane * 2 + row * 2) & (D - 1);
    const float2 w2 = *(const float2*)(emb + (size_t)row * D + e0);
    atomicAdd(&C[lab * D + e0],     w2.x * inv);
    atomicAdd(&C[lab * D + e0 + 1], w2.y * inv);
    if (lane == 0) atomicAdd(&cnt[lab], 1);
}

// Kernel 2: z only. Block = 4 waves; wave owns 64 i-rows (4 groups of 16).
// grid (N/IBLK, JSPLIT). No LDS, no barriers; B direct from global (L1/L2).
__global__ __launch_bounds__(256) void zsum_kernel(
        const unsigned char* __restrict__ ebf, float* __restrict__ z) {
    const int t    = threadIdx.x;
    const int w    = t >> 6;
    const int lane = t & 63;
    const int q    = lane >> 4;
    const int col  = lane & 15;
    const int iw   = blockIdx.x * IBLK + w * 64;
    const int jb   = blockIdx.y * (N / JSPLIT);

    bf16x8 a[4][4];
    #pragma unroll
    for (int g = 0; g < 4; ++g) {
        const unsigned char* ag = ebf + (size_t)(iw / 16 + g) * 4096 + lane * 16;
        #pragma unroll
        for (int c = 0; c < 4; ++c) a[g][c] = *(const bf16x8*)(ag + c * 1024);
    }

    float zacc[4][4] = {{0.f,0.f,0.f,0.f},{0.f,0.f,0.f,0.f},
                        {0.f,0.f,0.f,0.f},{0.f,0.f,0.f,0.f}};

    #pragma unroll 4
    for (int jt = 0; jt < (N / JSPLIT) / 16; ++jt) {
        const int js = jb + jt * 16;
        const unsigned char* bg = ebf + (size_t)(js / 16) * 4096 + lane * 16;
        bf16x8 b[4];
        #pragma unroll
        for (int c = 0; c < 4; ++c) b[c] = *(const bf16x8*)(bg + c * 1024);

        #pragma unroll
        for (int g = 0; g < 4; ++g) {
            f32x4 acc = {0.f, 0.f, 0.f, 0.f};
            #pragma unroll
            for (int c = 0; c < 4; ++c)
                acc = __builtin_amdgcn_mfma_f32_16x16x32_bf16(a[g][c], b[c], acc, 0, 0, 0);
            if (js == iw + g * 16) {                  // wave-uniform diagonal tile
                #pragma unroll
                for (int r = 0; r < 4; ++r)
                    zacc[g][r] += (col == q * 4 + r)
                        ? 0.0f : fast_exp2(fmaf(acc[r], K2E, -K2E));
            } else {
                #pragma unroll
                for (int r = 0; r < 4; ++r)
                    zacc[g][r] += fast_exp2(fmaf(acc[r], K2E, -K2E));
            }
        }
    }

    #pragma unroll
    for (int g = 0; g < 4; ++g)
        #pragma unroll
        for (int r = 0; r < 4; ++r) {
            float zv = zacc[g][r];
            zv += __shfl_xor(zv, 1);
            zv += __shfl_xor(zv, 2);
            zv += __shfl_xor(zv, 4);
            zv += __shfl_xor(zv, 8);
            if (col == 0) atomicAdd(&z[iw + g * 16 + q * 4 + r], zv);
        }
}

// Kernel 3: per-row assembly. Wave handles 4 rows; block = 16 rows.
__global__ __launch_bounds__(256) void final_kernel(
        const float* __restrict__ emb, const int* __restrict__ labels,
        const float* __restrict__ C, const int* __restrict__ cnt,
        const float* __restrict__ z, float* __restrict__ out) {
    __shared__ float part[4];
    const int wave = threadIdx.x >> 6;
    const int lane = threadIdx.x & 63;

    float wsum = 0.0f;
    #pragma unroll
    for (int r = 0; r < 4; ++r) {
        const int row = blockIdx.x * 16 + wave * 4 + r;
        const int lab = labels[row];
        const float2 v  = *(const float2*)(emb + (size_t)row * D + lane * 2);
        const float2 c2 = *(const float2*)(C   + (size_t)lab * D + lane * 2);
        float ss = v.x * v.x + v.y * v.y;
        float d  = v.x * c2.x + v.y * c2.y;
        #pragma unroll
        for (int off = 32; off; off >>= 1) {
            ss += __shfl_xor(ss, off);
            d  += __shfl_xor(d,  off);
        }
        if (lane == 0) {
            const int P = cnt[lab] - 1;
            if (P > 0) {
                const float inv  = 1.0f / fmaxf(sqrtf(ss), 1e-12f);
                const float logz = 10.0f + 0.69314718056f * fast_log2(z[row]);
                const float S    = (d * inv) * 10.0f - 10.0f;  // 10*possum
                wsum += (float)P * logz - S;
            }
        }
    }
    if (lane == 0) part[wave] = wsum;
    __syncthreads();
    if (threadIdx.x == 0) {
        const float tt = part[0] + part[1] + part[2] + part[3];
        atomicAdd(out, tt * (1.0f / (float)N));
    }
}

extern "C" void kernel_launch(void* const* d_in, const int* in_sizes, int n_in,
                              void* d_out, int out_size, void* d_ws, size_t ws_size,
                              hipStream_t stream) {
    const float* emb  = (const float*)d_in[0];
    const int* labels = (const int*)d_in[1];
    float* out        = (float*)d_out;
    char* ws          = (char*)d_ws;

    unsigned char* ebf = (unsigned char*)(ws + EBF_OFF);
    float* C           = (float*)(ws + C_OFF);
    int*   cnt         = (int*)(ws + CNT_OFF);
    float* z           = (float*)(ws + Z_OFF);

    hipMemsetAsync(ws + C_OFF, 0, ZERO_SZ, stream);
    hipMemsetAsync(d_out, 0, sizeof(float), stream);

    prep_kernel<<<N / 4, 256, 0, stream>>>(emb, labels, ebf, C, cnt);
    zsum_kernel<<<dim3(N / IBLK, JSPLIT), 256, 0, stream>>>(ebf, z);
    final_kernel<<<N / 16, 256, 0, stream>>>(emb, labels, C, cnt, z, out);
}